// Round 1
// baseline (36.702 us; speedup 1.0000x reference)
//
#include <hip/hip_runtime.h>

// LearnedClassVectors: bucketize HU intensities -> gather class vectors ->
// patchify (P=4) -> channel-first output (B, 768, nD, nH, nW).
//
// Output element: out[b, f, nd, nh, nw] = vectors[idx[b, nd*4+pd, nh*4+ph, nw*4+pw], v]
// with f = ((pd*4+ph)*4+pw)*12 + v and idx = max(1, count(interval <= x)).

#define THREADS 256

__global__ __launch_bounds__(THREADS)
void lcv_kernel(const float* __restrict__ x,
                const float* __restrict__ vecs,
                float* __restrict__ out) {
    // sidx layout: [q = (pd*4+ph)*4+pw][nw]  (64 rows x 32 ints = 8 KB)
    __shared__ int   sidx[64 * 32];
    __shared__ float svec[13 * 12];

    const int t   = threadIdx.x;
    const int blk = blockIdx.x;
    const int nh  = blk & 31;
    const int nd  = (blk >> 5) & 31;
    const int b   = blk >> 10;

    if (t < 13 * 12) svec[t] = vecs[t];

    // HU interval edges (searchsorted side='right' == count(edge <= x))
    const float I0 = -1000.f, I1 = -900.f, I2 = -400.f, I3 = -100.f;
    const float I4 = -50.f,   I5 = -10.f,  I6 = 20.f,   I7 = 40.f;
    const float I8 = 60.f,    I9 = 100.f,  I10 = 800.f, I11 = 1000.f;

    // x strides (floats): b: 128^3, d: 128*128, h: 128, w: 1
    const int xbase = b * 2097152 + (nd * 4) * 16384 + (nh * 4) * 128;

    // Phase 1: load 4x4x128 slab (512 float4), bucketize, store permuted to LDS.
    #pragma unroll
    for (int k = 0; k < 2; ++k) {
        const int i      = t + THREADS * k;   // float4 slot, 0..511
        const int pd     = i >> 7;            // 0..3
        const int within = i & 127;           // float4 index inside 512-float chunk
        const float4 v4  = *reinterpret_cast<const float4*>(
                               x + xbase + pd * 16384 + within * 4);
        const float vals[4] = {v4.x, v4.y, v4.z, v4.w};
        // voxel pos = within*4+c = ph*128 + w;  ph = within>>5, w&3 = c, w>>2 = within&31
        const int lbase = ((pd * 4 + (within >> 5)) * 4) * 32 + (within & 31);
        #pragma unroll
        for (int c = 0; c < 4; ++c) {
            const float v = vals[c];
            int si = (v >= I0) + (v >= I1) + (v >= I2)  + (v >= I3) +
                     (v >= I4) + (v >= I5) + (v >= I6)  + (v >= I7) +
                     (v >= I8) + (v >= I9) + (v >= I10) + (v >= I11);
            si = si < 1 ? 1 : si;   // bucket 0 merged into 1 (reference quirk)
            sidx[lbase + c * 32] = si;
        }
    }
    __syncthreads();

    // Phase 2: 768 f-rows x 32 nw = 6144 float4 stores per block, 24/thread.
    // out strides (floats): b: 768*32768, f: 32768, nd: 1024, nh: 32, nw: 1
    const int obase = b * 25165824 + nd * 1024 + nh * 32;
    #pragma unroll
    for (int r = 0; r < 24; ++r) {
        const int s = t + THREADS * r;   // float4 slot, 0..6143
        const int f = s >> 3;            // output channel, 0..767
        const int g = s & 7;             // nw group of 4
        const int v = f % 12;
        const int q = f / 12;            // (pd*4+ph)*4+pw == sidx row
        const int4 si4 = *reinterpret_cast<const int4*>(&sidx[q * 32 + g * 4]);
        float4 ov;
        ov.x = svec[si4.x * 12 + v];
        ov.y = svec[si4.y * 12 + v];
        ov.z = svec[si4.z * 12 + v];
        ov.w = svec[si4.w * 12 + v];
        *reinterpret_cast<float4*>(out + obase + f * 32768 + g * 4) = ov;
    }
}

extern "C" void kernel_launch(void* const* d_in, const int* in_sizes, int n_in,
                              void* d_out, int out_size, void* d_ws, size_t ws_size,
                              hipStream_t stream) {
    const float* x    = (const float*)d_in[0];
    const float* vecs = (const float*)d_in[1];
    float* out        = (float*)d_out;
    const int B = in_sizes[0] / 2097152;   // 128^3 voxels per batch (C==1)
    lcv_kernel<<<dim3(B * 32 * 32), THREADS, 0, stream>>>(x, vecs, out);
}